// Round 2
// baseline (2180.712 us; speedup 1.0000x reference)
//
#include <hip/hip_runtime.h>
#include <math.h>

#define BATCH 4
#define SEQ 2048
#define DMODEL 1024
#define NHEAD 16
#define DHEAD 64
#define MTOT (BATCH * SEQ)   /* 8192 */
#define LN_EPS 1e-5f

typedef float f4 __attribute__((ext_vector_type(4)));

// ---------------------------------------------------------------------------
// Tiled fp32 SGEMM: C[M,N] = A[M,K] @ B[K,N] + bias[N]
// 64x64 block tile, BK=16, 256 threads, 4x4 microtile per thread.
// ---------------------------------------------------------------------------
__global__ __launch_bounds__(256) void sgemm_bias(
    const float* __restrict__ A, const float* __restrict__ Bm,
    const float* __restrict__ bias, float* __restrict__ C,
    int M, int N, int K)
{
    __shared__ float As[16][64];   // [k][m] (transposed store)
    __shared__ float Bs[16][64];   // [k][n]

    const int t  = threadIdx.x;
    const int tx = t & 15;         // n-microtile index
    const int ty = t >> 4;         // m-microtile index
    const int m0 = blockIdx.y * 64;
    const int n0 = blockIdx.x * 64;

    const int arow = t & 63;       // A tile row   (0..63)
    const int akg  = t >> 6;       // A k-group    (0..3) -> 4 k's each
    const int brow = t >> 4;       // B tile row   (0..15)
    const int bcol = (t & 15) * 4; // B tile col

    float acc[4][4] = {};

    for (int k0 = 0; k0 < K; k0 += 16) {
        f4 a = *(const f4*)&A[(size_t)(m0 + arow) * K + k0 + akg * 4];
        f4 b = *(const f4*)&Bm[(size_t)(k0 + brow) * N + n0 + bcol];
        __syncthreads();   // previous iteration's reads done before overwrite
        As[akg * 4 + 0][arow] = a[0];
        As[akg * 4 + 1][arow] = a[1];
        As[akg * 4 + 2][arow] = a[2];
        As[akg * 4 + 3][arow] = a[3];
        *(f4*)&Bs[brow][bcol] = b;
        __syncthreads();
#pragma unroll
        for (int kk = 0; kk < 16; ++kk) {
            f4 av = *(f4*)&As[kk][ty * 4];
            f4 bv = *(f4*)&Bs[kk][tx * 4];
#pragma unroll
            for (int i = 0; i < 4; ++i)
#pragma unroll
                for (int j = 0; j < 4; ++j)
                    acc[i][j] += av[i] * bv[j];
        }
    }

    f4 bv = *(const f4*)&bias[n0 + tx * 4];
#pragma unroll
    for (int i = 0; i < 4; ++i) {
        f4 ov;
#pragma unroll
        for (int j = 0; j < 4; ++j) ov[j] = acc[i][j] + bv[j];
        *(f4*)&C[(size_t)(m0 + ty * 4 + i) * N + n0 + tx * 4] = ov;
    }
}

// ---------------------------------------------------------------------------
// Flash attention, fp32. One block = one (b, h, 64-query tile).
// qkv: base of workspace, q at +0, k at +M*D, v at +2*M*D (layout [B*S, 1024],
// head h occupies columns h*64 .. h*64+63).
// ctx aliases the q region (each block reads its own q slice first, writes its
// own ctx slice last; slices are disjoint across blocks).
// ---------------------------------------------------------------------------
__global__ __launch_bounds__(256) void flash_attn(
    const float* qkv, float* ctx)
{
    __shared__ float Qst[64][64];  // [d][q], pre-scaled by 1/8
    __shared__ float Kst[64][64];  // [d][k]
    __shared__ float Vs[64][64];   // [k][dv]
    __shared__ float Ps[64][64];   // [q][k]

    const int t  = threadIdx.x;
    const int tx = t & 15;
    const int ty = t >> 4;
    const int qt = blockIdx.x;
    const int h  = blockIdx.y;
    const int b  = blockIdx.z;

    const float* qp = qkv;
    const float* kp = qkv + (size_t)MTOT * DMODEL;
    const float* vp = qkv + (size_t)2 * MTOT * DMODEL;

    const int q0   = qt * 64;
    const int lrow = t & 63;   // tile row (q or kv index)
    const int dg   = t >> 6;   // owns head-dims [dg*16, dg*16+16)

    { // load + transpose Q tile, pre-scaled by 1/sqrt(64)
        const float* src = &qp[(size_t)(b * SEQ + q0 + lrow) * DMODEL + h * DHEAD + dg * 16];
#pragma unroll
        for (int u = 0; u < 4; ++u) {
            f4 v = *(const f4*)&src[u * 4];
#pragma unroll
            for (int w = 0; w < 4; ++w) Qst[dg * 16 + u * 4 + w][lrow] = v[w] * 0.125f;
        }
    }

    float m_[4], l_[4], o_[4][4];
#pragma unroll
    for (int i = 0; i < 4; ++i) {
        m_[i] = -1e30f; l_[i] = 0.f;
#pragma unroll
        for (int j = 0; j < 4; ++j) o_[i][j] = 0.f;
    }

    for (int kv0 = 0; kv0 < SEQ; kv0 += 64) {
        const float* ksrc = &kp[(size_t)(b * SEQ + kv0 + lrow) * DMODEL + h * DHEAD + dg * 16];
        const float* vsrc = &vp[(size_t)(b * SEQ + kv0 + lrow) * DMODEL + h * DHEAD + dg * 16];
        f4 kv[4], vv[4];
#pragma unroll
        for (int u = 0; u < 4; ++u) { kv[u] = *(const f4*)&ksrc[u * 4]; vv[u] = *(const f4*)&vsrc[u * 4]; }
        __syncthreads();  // prev iter's Kst/Vs/Ps reads complete
#pragma unroll
        for (int u = 0; u < 4; ++u) {
#pragma unroll
            for (int w = 0; w < 4; ++w) Kst[dg * 16 + u * 4 + w][lrow] = kv[u][w];
            *(f4*)&Vs[lrow][dg * 16 + u * 4] = vv[u];
        }
        __syncthreads();

        // S = (Q/8) K^T   -> s[i][j], rows q=ty*4+i, cols k=tx*4+j
        float s[4][4] = {};
#pragma unroll 8
        for (int d = 0; d < 64; ++d) {
            f4 qv = *(f4*)&Qst[d][ty * 4];
            f4 kvv = *(f4*)&Kst[d][tx * 4];
#pragma unroll
            for (int i = 0; i < 4; ++i)
#pragma unroll
                for (int j = 0; j < 4; ++j)
                    s[i][j] += qv[i] * kvv[j];
        }

        // online softmax (row reduce across the 16-lane tx group)
        float p[4][4];
#pragma unroll
        for (int i = 0; i < 4; ++i) {
            float rmax = fmaxf(fmaxf(s[i][0], s[i][1]), fmaxf(s[i][2], s[i][3]));
#pragma unroll
            for (int off = 1; off < 16; off <<= 1)
                rmax = fmaxf(rmax, __shfl_xor(rmax, off));
            float mnew = fmaxf(m_[i], rmax);
            float fs = __expf(m_[i] - mnew);
            float rsum = 0.f;
#pragma unroll
            for (int j = 0; j < 4; ++j) { p[i][j] = __expf(s[i][j] - mnew); rsum += p[i][j]; }
#pragma unroll
            for (int off = 1; off < 16; off <<= 1)
                rsum += __shfl_xor(rsum, off);
            l_[i] = l_[i] * fs + rsum;
            m_[i] = mnew;
#pragma unroll
            for (int j = 0; j < 4; ++j) o_[i][j] *= fs;
        }

        // stash P tile [q][k]
#pragma unroll
        for (int i = 0; i < 4; ++i)
            *(f4*)&Ps[ty * 4 + i][tx * 4] = (f4){p[i][0], p[i][1], p[i][2], p[i][3]};
        __syncthreads();

        // O += P V : o[i][j] over rows q=ty*4+i, cols dv=tx*4+j
#pragma unroll 4
        for (int k4 = 0; k4 < 64; k4 += 4) {
            f4 pr0 = *(f4*)&Ps[ty * 4 + 0][k4];
            f4 pr1 = *(f4*)&Ps[ty * 4 + 1][k4];
            f4 pr2 = *(f4*)&Ps[ty * 4 + 2][k4];
            f4 pr3 = *(f4*)&Ps[ty * 4 + 3][k4];
#pragma unroll
            for (int kk = 0; kk < 4; ++kk) {
                f4 vr = *(f4*)&Vs[k4 + kk][tx * 4];
#pragma unroll
                for (int j = 0; j < 4; ++j) {
                    o_[0][j] += pr0[kk] * vr[j];
                    o_[1][j] += pr1[kk] * vr[j];
                    o_[2][j] += pr2[kk] * vr[j];
                    o_[3][j] += pr3[kk] * vr[j];
                }
            }
        }
        // loop-top barrier protects Ps/Vs before next overwrite
    }

#pragma unroll
    for (int i = 0; i < 4; ++i) {
        float inv = 1.0f / l_[i];
        f4 ov;
#pragma unroll
        for (int j = 0; j < 4; ++j) ov[j] = o_[i][j] * inv;
        *(f4*)&ctx[(size_t)(b * SEQ + q0 + ty * 4 + i) * DMODEL + h * DHEAD + tx * 4] = ov;
    }
}

// ---------------------------------------------------------------------------
// out = LayerNorm(x + res) * g + b, rows of 1024. One block per row.
// ---------------------------------------------------------------------------
__global__ __launch_bounds__(256) void ln_residual(
    const float* __restrict__ x, const float* __restrict__ res,
    const float* __restrict__ g, const float* __restrict__ bb,
    float* __restrict__ out)
{
    const int row = blockIdx.x;
    const int t = threadIdx.x;
    f4 xv = *(const f4*)&x[(size_t)row * DMODEL + t * 4];
    f4 rv = *(const f4*)&res[(size_t)row * DMODEL + t * 4];
    f4 v;
#pragma unroll
    for (int u = 0; u < 4; ++u) v[u] = xv[u] + rv[u];

    float s = 0.f, s2 = 0.f;
#pragma unroll
    for (int u = 0; u < 4; ++u) { s += v[u]; s2 += v[u] * v[u]; }
#pragma unroll
    for (int off = 1; off < 64; off <<= 1) {
        s  += __shfl_xor(s, off);
        s2 += __shfl_xor(s2, off);
    }
    __shared__ float red[2][4];
    const int wid = t >> 6, lane = t & 63;
    if (lane == 0) { red[0][wid] = s; red[1][wid] = s2; }
    __syncthreads();
    s  = red[0][0] + red[0][1] + red[0][2] + red[0][3];
    s2 = red[1][0] + red[1][1] + red[1][2] + red[1][3];

    const float mean = s * (1.0f / DMODEL);
    const float var  = s2 * (1.0f / DMODEL) - mean * mean;
    const float rstd = rsqrtf(var + LN_EPS);

    f4 gv = *(const f4*)&g[t * 4];
    f4 bv = *(const f4*)&bb[t * 4];
    f4 ov;
#pragma unroll
    for (int u = 0; u < 4; ++u) ov[u] = (v[u] - mean) * rstd * gv[u] + bv[u];
    *(f4*)&out[(size_t)row * DMODEL + t * 4] = ov;
}

// ---------------------------------------------------------------------------
extern "C" void kernel_launch(void* const* d_in, const int* in_sizes, int n_in,
                              void* d_out, int out_size, void* d_ws, size_t ws_size,
                              hipStream_t stream)
{
    const float* Q   = (const float*)d_in[0];
    const float* Wq  = (const float*)d_in[1];
    const float* bq  = (const float*)d_in[2];
    const float* Wk  = (const float*)d_in[3];
    const float* bk  = (const float*)d_in[4];
    const float* Wv  = (const float*)d_in[5];
    const float* bv  = (const float*)d_in[6];
    const float* Wo  = (const float*)d_in[7];
    const float* bo  = (const float*)d_in[8];
    const float* lng = (const float*)d_in[9];
    const float* lnb = (const float*)d_in[10];

    float* ws  = (float*)d_ws;
    float* q   = ws;                              // [8192,1024], later ctx
    float* k   = ws + (size_t)MTOT * DMODEL;      // later attn-out
    float* v   = ws + (size_t)2 * MTOT * DMODEL;

    dim3 gg(DMODEL / 64, MTOT / 64);              // (16, 128)
    sgemm_bias<<<gg, 256, 0, stream>>>(Q, Wq, bq, q, MTOT, DMODEL, DMODEL);
    sgemm_bias<<<gg, 256, 0, stream>>>(Q, Wk, bk, k, MTOT, DMODEL, DMODEL);
    sgemm_bias<<<gg, 256, 0, stream>>>(Q, Wv, bv, v, MTOT, DMODEL, DMODEL);

    dim3 ga(SEQ / 64, NHEAD, BATCH);              // (32, 16, 4)
    flash_attn<<<ga, 256, 0, stream>>>(ws, q);    // ctx overwrites q region

    sgemm_bias<<<gg, 256, 0, stream>>>(q, Wo, bo, k, MTOT, DMODEL, DMODEL);

    ln_residual<<<MTOT, 256, 0, stream>>>(k, Q, lng, lnb, (float*)d_out);
}

// Round 3
// 387.247 us; speedup vs baseline: 5.6313x; 5.6313x over previous
//
#include <hip/hip_runtime.h>
#include <math.h>

#define BATCH 4
#define SEQ 2048
#define DMODEL 1024
#define NHEAD 16
#define DHEAD 64
#define MTOT (BATCH * SEQ)   /* 8192 */
#define LN_EPS 1e-5f

typedef float f4 __attribute__((ext_vector_type(4)));
typedef float f32x4 __attribute__((ext_vector_type(4)));
typedef __bf16 bf16_t;
typedef __bf16 bf16x8 __attribute__((ext_vector_type(8)));
typedef __bf16 bf16x4 __attribute__((ext_vector_type(4)));

// async global->LDS, 16B per lane; dest = wave-uniform base + lane*16
__device__ __forceinline__ void gload_lds16(const bf16_t* g, bf16_t* l) {
    __builtin_amdgcn_global_load_lds(
        (const __attribute__((address_space(1))) void*)g,
        (__attribute__((address_space(3))) void*)l, 16, 0, 0);
}

// ---------------------------------------------------------------------------
// fp32 -> bf16 elementwise (n4 = count of float4 groups)
// ---------------------------------------------------------------------------
__global__ __launch_bounds__(256) void cvt_bf16(
    const float* __restrict__ x, bf16_t* __restrict__ y, int n4)
{
    for (int i = blockIdx.x * 256 + threadIdx.x; i < n4; i += gridDim.x * 256) {
        f4 v = *(const f4*)&x[(size_t)i * 4];
        bf16x4 o;
        o[0] = (bf16_t)v[0]; o[1] = (bf16_t)v[1];
        o[2] = (bf16_t)v[2]; o[3] = (bf16_t)v[3];
        *(bf16x4*)&y[(size_t)i * 4] = o;
    }
}

// ---------------------------------------------------------------------------
// W[k][n] fp32 -> Wt[n][k] bf16 (32x32 LDS tiles)
// ---------------------------------------------------------------------------
__global__ __launch_bounds__(256) void wtrans(
    const float* __restrict__ W, bf16_t* __restrict__ Wt)
{
    __shared__ float tile[32][33];
    const int n0 = blockIdx.x * 32, k0 = blockIdx.y * 32;
    const int c = threadIdx.x & 31, rr = threadIdx.x >> 5;   // 8 rows/pass
#pragma unroll
    for (int i = 0; i < 32; i += 8)
        tile[rr + i][c] = W[(size_t)(k0 + rr + i) * DMODEL + n0 + c];
    __syncthreads();
#pragma unroll
    for (int i = 0; i < 32; i += 8)
        Wt[(size_t)(n0 + rr + i) * DMODEL + k0 + c] = (bf16_t)tile[c][rr + i];
}

// ---------------------------------------------------------------------------
// bf16 MFMA GEMM: C[M=8192][1024] = A[M][1024] @ Bt[n][k]^T + bias
// 128x128 tile, BK=32, 4 waves (2x2), 16x16x32 MFMA, global_load_lds(16B)
// LDS swizzle: byte ^= ((byte>>7)&3)<<4 (read side); source pre-swizzled.
// ---------------------------------------------------------------------------
template<int OUT_BF16>
__global__ __launch_bounds__(256) void gemm_mfma(
    const bf16_t* __restrict__ A, const bf16_t* __restrict__ Bt,
    const float* __restrict__ bias, void* __restrict__ Cout)
{
    __shared__ bf16_t As[128 * 32];
    __shared__ bf16_t Bs[128 * 32];
    const int t = threadIdx.x;
    const int w = t >> 6, lane = t & 63;
    const int r16 = lane & 15, g = lane >> 4;
    const int m0 = blockIdx.y * 128, n0 = blockIdx.x * 128;
    const int wr = w >> 1, wc = w & 1;

    // staging: issue r in {0,1}: dest byte y = r*4096 + w*1024 + lane*16
    const int y0 = w * 1024 + lane * 16;
    const int y1 = y0 + 4096;
    const int row0 = y0 >> 6, row1 = y1 >> 6;
    const int sl0 = ((y0 >> 4) & 3) ^ ((row0 >> 1) & 3);
    const int sl1 = ((y1 >> 4) & 3) ^ ((row1 >> 1) & 3);
    const bf16_t* a0 = A + (size_t)(m0 + row0) * DMODEL + sl0 * 8;
    const bf16_t* a1 = A + (size_t)(m0 + row1) * DMODEL + sl1 * 8;
    const bf16_t* b0 = Bt + (size_t)(n0 + row0) * DMODEL + sl0 * 8;
    const bf16_t* b1 = Bt + (size_t)(n0 + row1) * DMODEL + sl1 * 8;
    bf16_t* da0 = As + w * 512;
    bf16_t* da1 = As + 2048 + w * 512;
    bf16_t* db0 = Bs + w * 512;
    bf16_t* db1 = Bs + 2048 + w * 512;

    // fragment read offsets (elements), swizzled
    int aoff[4], boff[4];
#pragma unroll
    for (int i = 0; i < 4; ++i) {
        int ar = wr * 64 + i * 16 + r16;
        int al = ar * 64 + g * 16;
        al ^= ((ar >> 1) & 3) << 4;
        aoff[i] = al >> 1;
        int br = wc * 64 + i * 16 + r16;
        int bl = br * 64 + g * 16;
        bl ^= ((br >> 1) & 3) << 4;
        boff[i] = bl >> 1;
    }

    const f32x4 z4 = {0.f, 0.f, 0.f, 0.f};
    f32x4 acc[4][4];
#pragma unroll
    for (int i = 0; i < 4; ++i)
#pragma unroll
        for (int j = 0; j < 4; ++j) acc[i][j] = z4;

    for (int k0 = 0; k0 < DMODEL; k0 += 32) {
        __syncthreads();                 // prior LDS reads complete
        gload_lds16(a0 + k0, da0);
        gload_lds16(a1 + k0, da1);
        gload_lds16(b0 + k0, db0);
        gload_lds16(b1 + k0, db1);
        __syncthreads();                 // barrier drains vmcnt -> tiles ready
        bf16x8 af[4], bfr[4];
#pragma unroll
        for (int i = 0; i < 4; ++i) af[i] = *(const bf16x8*)&As[aoff[i]];
#pragma unroll
        for (int j = 0; j < 4; ++j) bfr[j] = *(const bf16x8*)&Bs[boff[j]];
#pragma unroll
        for (int i = 0; i < 4; ++i)
#pragma unroll
            for (int j = 0; j < 4; ++j)
                acc[i][j] = __builtin_amdgcn_mfma_f32_16x16x32_bf16(
                    af[i], bfr[j], acc[i][j], 0, 0, 0);
    }

    // epilogue: D row = (lane>>4)*4 + reg, col = lane&15  (m89-verified)
#pragma unroll
    for (int j = 0; j < 4; ++j) {
        const int col = n0 + wc * 64 + j * 16 + r16;
        const float bv = bias[col];
#pragma unroll
        for (int i = 0; i < 4; ++i) {
            const int rbase = m0 + wr * 64 + i * 16 + g * 4;
#pragma unroll
            for (int rr = 0; rr < 4; ++rr) {
                float vv = acc[i][j][rr] + bv;
                if (OUT_BF16)
                    ((bf16_t*)Cout)[(size_t)(rbase + rr) * DMODEL + col] = (bf16_t)vv;
                else
                    ((float*)Cout)[(size_t)(rbase + rr) * DMODEL + col] = vv;
            }
        }
    }
}

// ---------------------------------------------------------------------------
// MFMA flash attention. Block = (b, h, 64-query tile), 4 waves, 16 q-rows/wave.
// K: swizzled global_load_lds; V: reg-staged transposed to Vt[dim][key];
// P: D-layout -> LDS -> A-layout. ctx may alias qg (reads precede writes,
// ordered by the in-loop barriers).
// ---------------------------------------------------------------------------
__global__ __launch_bounds__(256) void flash_mfma(
    const bf16_t* __restrict__ qg, const bf16_t* __restrict__ kg,
    const bf16_t* __restrict__ vg, bf16_t* __restrict__ ctx)
{
    __shared__ bf16_t Ks[64 * 64];   // [key][dim], byte ^= (key&7)<<4
    __shared__ bf16_t Vt[64 * 72];   // [dim][key], padded pitch 72
    __shared__ bf16_t Ps[64 * 72];   // [q][key],  padded pitch 72

    const int t = threadIdx.x;
    const int w = t >> 6, lane = t & 63;
    const int r16 = lane & 15, g = lane >> 4;
    const int q0 = blockIdx.x * 64, h = blockIdx.y, b = blockIdx.z;

    // Q fragments in registers: row = q0+16w+r16, k = kc*32 + g*8 + j
    bf16x8 qf0, qf1;
    {
        const bf16_t* qrow = qg + (size_t)(b * SEQ + q0 + 16 * w + r16) * DMODEL + h * DHEAD;
        qf0 = *(const bf16x8*)&qrow[g * 8];
        qf1 = *(const bf16x8*)&qrow[32 + g * 8];
    }

    // K staging: issue r: dest byte y = r*4096 + w*1024 + lane*16
    const int yk0 = w * 1024 + lane * 16;
    const int yk1 = yk0 + 4096;
    const int kr0 = yk0 >> 7, kr1 = yk1 >> 7;
    const int ks0 = ((yk0 >> 4) & 7) ^ (kr0 & 7);
    const int ks1 = ((yk1 >> 4) & 7) ^ (kr1 & 7);
    const bf16_t* kb0 = kg + (size_t)(b * SEQ + kr0) * DMODEL + h * DHEAD + ks0 * 8;
    const bf16_t* kb1 = kg + (size_t)(b * SEQ + kr1) * DMODEL + h * DHEAD + ks1 * 8;
    bf16_t* kd0 = Ks + w * 512;
    bf16_t* kd1 = Ks + 2048 + w * 512;

    // V staging: this thread loads key=lane, dims [w*16, w*16+16)
    const bf16_t* vb = vg + (size_t)(b * SEQ + lane) * DMODEL + h * DHEAD + w * 16;

    // K fragment offsets (elements), swizzled
    int koff[4][2];
#pragma unroll
    for (int nj = 0; nj < 4; ++nj) {
        const int key = nj * 16 + r16;
#pragma unroll
        for (int kc = 0; kc < 2; ++kc) {
            int lin = key * 128 + kc * 64 + g * 16;
            lin ^= (key & 7) << 4;
            koff[nj][kc] = lin >> 1;
        }
    }

    const f32x4 z4 = {0.f, 0.f, 0.f, 0.f};
    float m_[4], l_[4];
    f32x4 o_[4];
#pragma unroll
    for (int i = 0; i < 4; ++i) { m_[i] = -1e30f; l_[i] = 0.f; o_[i] = z4; }

    for (int kv0 = 0; kv0 < SEQ; kv0 += 64) {
        // V tile -> regs early (latency hides under barrier/stage)
        const bf16_t* vv = vb + (size_t)kv0 * DMODEL;
        bf16x8 v0 = *(const bf16x8*)&vv[0];
        bf16x8 v1 = *(const bf16x8*)&vv[8];
        __syncthreads();   // prior reads of Ks/Vt/Ps complete
        gload_lds16(kb0 + (size_t)kv0 * DMODEL, kd0);
        gload_lds16(kb1 + (size_t)kv0 * DMODEL, kd1);
#pragma unroll
        for (int e = 0; e < 8; ++e) {
            Vt[(w * 16 + e) * 72 + lane]     = v0[e];
            Vt[(w * 16 + 8 + e) * 72 + lane] = v1[e];
        }
        __syncthreads();   // K staged (barrier drains vmcnt), Vt visible

        // S = Q K^T : s[nj] covers keys 16nj+r16, rows 16w + g*4 + rr
        f32x4 s[4];
#pragma unroll
        for (int nj = 0; nj < 4; ++nj) {
            bf16x8 kf0 = *(const bf16x8*)&Ks[koff[nj][0]];
            bf16x8 kf1 = *(const bf16x8*)&Ks[koff[nj][1]];
            s[nj] = __builtin_amdgcn_mfma_f32_16x16x32_bf16(qf0, kf0, z4, 0, 0, 0);
            s[nj] = __builtin_amdgcn_mfma_f32_16x16x32_bf16(qf1, kf1, s[nj], 0, 0, 0);
        }

        // online softmax; row-reduce = shfl over the 16 col-lanes + nj regs
        float mx[4];
#pragma unroll
        for (int rr = 0; rr < 4; ++rr)
            mx[rr] = fmaxf(fmaxf(s[0][rr], s[1][rr]), fmaxf(s[2][rr], s[3][rr])) * 0.125f;
#pragma unroll
        for (int off = 1; off < 16; off <<= 1)
#pragma unroll
            for (int rr = 0; rr < 4; ++rr)
                mx[rr] = fmaxf(mx[rr], __shfl_xor(mx[rr], off));

        float fs_[4];
#pragma unroll
        for (int rr = 0; rr < 4; ++rr) {
            const float mnew = fmaxf(m_[rr], mx[rr]);
            fs_[rr] = __expf(m_[rr] - mnew);
            m_[rr] = mnew;
        }
        float p[4][4];
        float rs[4] = {0.f, 0.f, 0.f, 0.f};
#pragma unroll
        for (int nj = 0; nj < 4; ++nj)
#pragma unroll
            for (int rr = 0; rr < 4; ++rr) {
                p[nj][rr] = __expf(s[nj][rr] * 0.125f - m_[rr]);
                rs[rr] += p[nj][rr];
            }
#pragma unroll
        for (int off = 1; off < 16; off <<= 1)
#pragma unroll
            for (int rr = 0; rr < 4; ++rr)
                rs[rr] += __shfl_xor(rs[rr], off);
#pragma unroll
        for (int rr = 0; rr < 4; ++rr) l_[rr] = l_[rr] * fs_[rr] + rs[rr];
#pragma unroll
        for (int nj = 0; nj < 4; ++nj) {
            f32x4 t4 = o_[nj];
            t4[0] *= fs_[0]; t4[1] *= fs_[1]; t4[2] *= fs_[2]; t4[3] *= fs_[3];
            o_[nj] = t4;
        }

        // P (D-layout) -> LDS bf16
#pragma unroll
        for (int nj = 0; nj < 4; ++nj)
#pragma unroll
            for (int rr = 0; rr < 4; ++rr)
                Ps[(16 * w + g * 4 + rr) * 72 + nj * 16 + r16] = (bf16_t)p[nj][rr];
        __syncthreads();   // Ps visible

        // O += P V : A-frag from Ps, B-frag from Vt
        bf16x8 pf0 = *(const bf16x8*)&Ps[(16 * w + r16) * 72 + g * 8];
        bf16x8 pf1 = *(const bf16x8*)&Ps[(16 * w + r16) * 72 + 32 + g * 8];
#pragma unroll
        for (int nj = 0; nj < 4; ++nj) {
            bf16x8 vf0 = *(const bf16x8*)&Vt[(nj * 16 + r16) * 72 + g * 8];
            bf16x8 vf1 = *(const bf16x8*)&Vt[(nj * 16 + r16) * 72 + 32 + g * 8];
            o_[nj] = __builtin_amdgcn_mfma_f32_16x16x32_bf16(pf0, vf0, o_[nj], 0, 0, 0);
            o_[nj] = __builtin_amdgcn_mfma_f32_16x16x32_bf16(pf1, vf1, o_[nj], 0, 0, 0);
        }
    }

    // write context (bf16)
#pragma unroll
    for (int rr = 0; rr < 4; ++rr) {
        const float inv = 1.0f / l_[rr];
        const size_t rowbase =
            (size_t)(b * SEQ + q0 + 16 * w + g * 4 + rr) * DMODEL + h * DHEAD;
#pragma unroll
        for (int nj = 0; nj < 4; ++nj)
            ctx[rowbase + nj * 16 + r16] = (bf16_t)(o_[nj][rr] * inv);
    }
}

// ---------------------------------------------------------------------------
// out = LayerNorm(x + res) * g + b, rows of 1024. One block per row.
// ---------------------------------------------------------------------------
__global__ __launch_bounds__(256) void ln_residual(
    const float* __restrict__ x, const float* __restrict__ res,
    const float* __restrict__ g, const float* __restrict__ bb,
    float* __restrict__ out)
{
    const int row = blockIdx.x;
    const int t = threadIdx.x;
    f4 xv = *(const f4*)&x[(size_t)row * DMODEL + t * 4];
    f4 rv = *(const f4*)&res[(size_t)row * DMODEL + t * 4];
    f4 v;
#pragma unroll
    for (int u = 0; u < 4; ++u) v[u] = xv[u] + rv[u];

    float s = 0.f, s2 = 0.f;
#pragma unroll
    for (int u = 0; u < 4; ++u) { s += v[u]; s2 += v[u] * v[u]; }
#pragma unroll
    for (int off = 1; off < 64; off <<= 1) {
        s  += __shfl_xor(s, off);
        s2 += __shfl_xor(s2, off);
    }
    __shared__ float red[2][4];
    const int wid = t >> 6, lane = t & 63;
    if (lane == 0) { red[0][wid] = s; red[1][wid] = s2; }
    __syncthreads();
    s  = red[0][0] + red[0][1] + red[0][2] + red[0][3];
    s2 = red[1][0] + red[1][1] + red[1][2] + red[1][3];

    const float mean = s * (1.0f / DMODEL);
    const float var  = s2 * (1.0f / DMODEL) - mean * mean;
    const float rstd = rsqrtf(var + LN_EPS);

    f4 gv = *(const f4*)&g[t * 4];
    f4 bv = *(const f4*)&bb[t * 4];
    f4 ov;
#pragma unroll
    for (int u = 0; u < 4; ++u) ov[u] = (v[u] - mean) * rstd * gv[u] + bv[u];
    *(f4*)&out[(size_t)row * DMODEL + t * 4] = ov;
}

// ---------------------------------------------------------------------------
extern "C" void kernel_launch(void* const* d_in, const int* in_sizes, int n_in,
                              void* d_out, int out_size, void* d_ws, size_t ws_size,
                              hipStream_t stream)
{
    const float* Q   = (const float*)d_in[0];
    const float* Wq  = (const float*)d_in[1];
    const float* bq  = (const float*)d_in[2];
    const float* Wk  = (const float*)d_in[3];
    const float* bk  = (const float*)d_in[4];
    const float* Wv  = (const float*)d_in[5];
    const float* bv  = (const float*)d_in[6];
    const float* Wo  = (const float*)d_in[7];
    const float* bo  = (const float*)d_in[8];
    const float* lng = (const float*)d_in[9];
    const float* lnb = (const float*)d_in[10];

    char* wsb = (char*)d_ws;
    // 0..16M: Qbf | 16..32M: q/ctx | 32..48M: k | 48..64M: v
    // 32..64M (after attn): attn_out fp32 | 64..72M: transposed bf16 weights
    bf16_t* Qbf  = (bf16_t*)(wsb);
    bf16_t* qb   = (bf16_t*)(wsb + (size_t)(16 << 20));
    bf16_t* kb   = (bf16_t*)(wsb + (size_t)(32 << 20));
    bf16_t* vbuf = (bf16_t*)(wsb + (size_t)(48 << 20));
    float*  ao   = (float*) (wsb + (size_t)(32 << 20));
    bf16_t* Wqt  = (bf16_t*)(wsb + (size_t)(64 << 20));
    bf16_t* Wkt  = (bf16_t*)(wsb + (size_t)(66 << 20));
    bf16_t* Wvt  = (bf16_t*)(wsb + (size_t)(68 << 20));
    bf16_t* Wot  = (bf16_t*)(wsb + (size_t)(70 << 20));

    cvt_bf16<<<2048, 256, 0, stream>>>(Q, Qbf, MTOT * DMODEL / 4);
    dim3 wg(32, 32);
    wtrans<<<wg, 256, 0, stream>>>(Wq, Wqt);
    wtrans<<<wg, 256, 0, stream>>>(Wk, Wkt);
    wtrans<<<wg, 256, 0, stream>>>(Wv, Wvt);
    wtrans<<<wg, 256, 0, stream>>>(Wo, Wot);

    dim3 gg(DMODEL / 128, MTOT / 128);            // (8, 64)
    gemm_mfma<1><<<gg, 256, 0, stream>>>(Qbf, Wqt, bq, qb);
    gemm_mfma<1><<<gg, 256, 0, stream>>>(Qbf, Wkt, bk, kb);
    gemm_mfma<1><<<gg, 256, 0, stream>>>(Qbf, Wvt, bv, vbuf);

    dim3 ga(SEQ / 64, NHEAD, BATCH);              // (32, 16, 4)
    flash_mfma<<<ga, 256, 0, stream>>>(qb, kb, vbuf, qb);  // ctx aliases q

    gemm_mfma<0><<<gg, 256, 0, stream>>>(qb, Wot, bo, ao);

    ln_residual<<<MTOT, 256, 0, stream>>>(ao, Q, lng, lnb, (float*)d_out);
}

// Round 4
// 310.125 us; speedup vs baseline: 7.0317x; 1.2487x over previous
//
#include <hip/hip_runtime.h>
#include <math.h>

#define BATCH 4
#define SEQ 2048
#define DMODEL 1024
#define NHEAD 16
#define DHEAD 64
#define MTOT (BATCH * SEQ)   /* 8192 */
#define LN_EPS 1e-5f

typedef float f4 __attribute__((ext_vector_type(4)));
typedef float f32x4 __attribute__((ext_vector_type(4)));
typedef __bf16 bf16_t;
typedef __bf16 bf16x8 __attribute__((ext_vector_type(8)));
typedef __bf16 bf16x4 __attribute__((ext_vector_type(4)));

// async global->LDS, 16B per lane; dest = wave-uniform base + lane*16
__device__ __forceinline__ void gload_lds16(const bf16_t* g, bf16_t* l) {
    __builtin_amdgcn_global_load_lds(
        (const __attribute__((address_space(1))) void*)g,
        (__attribute__((address_space(3))) void*)l, 16, 0, 0);
}

// ---------------------------------------------------------------------------
// fp32 -> bf16 elementwise (n4 = count of float4 groups)
// ---------------------------------------------------------------------------
__global__ __launch_bounds__(256) void cvt_bf16(
    const float* __restrict__ x, bf16_t* __restrict__ y, int n4)
{
    for (int i = blockIdx.x * 256 + threadIdx.x; i < n4; i += gridDim.x * 256) {
        f4 v = *(const f4*)&x[(size_t)i * 4];
        bf16x4 o;
        o[0] = (bf16_t)v[0]; o[1] = (bf16_t)v[1];
        o[2] = (bf16_t)v[2]; o[3] = (bf16_t)v[3];
        *(bf16x4*)&y[(size_t)i * 4] = o;
    }
}

// ---------------------------------------------------------------------------
// W[k][n] fp32 -> Wt[n][k] bf16 (32x32 LDS tiles)
// ---------------------------------------------------------------------------
__global__ __launch_bounds__(256) void wtrans(
    const float* __restrict__ W, bf16_t* __restrict__ Wt)
{
    __shared__ float tile[32][33];
    const int n0 = blockIdx.x * 32, k0 = blockIdx.y * 32;
    const int c = threadIdx.x & 31, rr = threadIdx.x >> 5;   // 8 rows/pass
#pragma unroll
    for (int i = 0; i < 32; i += 8)
        tile[rr + i][c] = W[(size_t)(k0 + rr + i) * DMODEL + n0 + c];
    __syncthreads();
#pragma unroll
    for (int i = 0; i < 32; i += 8)
        Wt[(size_t)(n0 + rr + i) * DMODEL + k0 + c] = (bf16_t)tile[c][rr + i];
}

// ---------------------------------------------------------------------------
// bf16 MFMA GEMM: C[M=8192][1024] = A[M][1024] @ Bt[n][k]^T + bias
// 128x128 tile, BK=32, 4 waves (2x2), 16x16x32 MFMA, global_load_lds(16B)
// LDS swizzle: byte ^= ((byte>>7)&3)<<4 (read side); source pre-swizzled.
// ---------------------------------------------------------------------------
template<int OUT_BF16>
__global__ __launch_bounds__(256) void gemm_mfma(
    const bf16_t* __restrict__ A, const bf16_t* __restrict__ Bt,
    const float* __restrict__ bias, void* __restrict__ Cout)
{
    __shared__ bf16_t As[128 * 32];
    __shared__ bf16_t Bs[128 * 32];
    const int t = threadIdx.x;
    const int w = t >> 6, lane = t & 63;
    const int r16 = lane & 15, g = lane >> 4;
    const int m0 = blockIdx.y * 128, n0 = blockIdx.x * 128;
    const int wr = w >> 1, wc = w & 1;

    // staging: issue r in {0,1}: dest byte y = r*4096 + w*1024 + lane*16
    const int y0 = w * 1024 + lane * 16;
    const int y1 = y0 + 4096;
    const int row0 = y0 >> 6, row1 = y1 >> 6;
    const int sl0 = ((y0 >> 4) & 3) ^ ((row0 >> 1) & 3);
    const int sl1 = ((y1 >> 4) & 3) ^ ((row1 >> 1) & 3);
    const bf16_t* a0 = A + (size_t)(m0 + row0) * DMODEL + sl0 * 8;
    const bf16_t* a1 = A + (size_t)(m0 + row1) * DMODEL + sl1 * 8;
    const bf16_t* b0 = Bt + (size_t)(n0 + row0) * DMODEL + sl0 * 8;
    const bf16_t* b1 = Bt + (size_t)(n0 + row1) * DMODEL + sl1 * 8;
    bf16_t* da0 = As + w * 512;
    bf16_t* da1 = As + 2048 + w * 512;
    bf16_t* db0 = Bs + w * 512;
    bf16_t* db1 = Bs + 2048 + w * 512;

    // fragment read offsets (elements), swizzled
    int aoff[4], boff[4];
#pragma unroll
    for (int i = 0; i < 4; ++i) {
        int ar = wr * 64 + i * 16 + r16;
        int al = ar * 64 + g * 16;
        al ^= ((ar >> 1) & 3) << 4;
        aoff[i] = al >> 1;
        int br = wc * 64 + i * 16 + r16;
        int bl = br * 64 + g * 16;
        bl ^= ((br >> 1) & 3) << 4;
        boff[i] = bl >> 1;
    }

    const f32x4 z4 = {0.f, 0.f, 0.f, 0.f};
    f32x4 acc[4][4];
#pragma unroll
    for (int i = 0; i < 4; ++i)
#pragma unroll
        for (int j = 0; j < 4; ++j) acc[i][j] = z4;

    for (int k0 = 0; k0 < DMODEL; k0 += 32) {
        __syncthreads();                 // prior LDS reads complete
        gload_lds16(a0 + k0, da0);
        gload_lds16(a1 + k0, da1);
        gload_lds16(b0 + k0, db0);
        gload_lds16(b1 + k0, db1);
        __syncthreads();                 // barrier drains vmcnt -> tiles ready
        bf16x8 af[4], bfr[4];
#pragma unroll
        for (int i = 0; i < 4; ++i) af[i] = *(const bf16x8*)&As[aoff[i]];
#pragma unroll
        for (int j = 0; j < 4; ++j) bfr[j] = *(const bf16x8*)&Bs[boff[j]];
#pragma unroll
        for (int i = 0; i < 4; ++i)
#pragma unroll
            for (int j = 0; j < 4; ++j)
                acc[i][j] = __builtin_amdgcn_mfma_f32_16x16x32_bf16(
                    af[i], bfr[j], acc[i][j], 0, 0, 0);
    }

    // epilogue: D row = (lane>>4)*4 + reg, col = lane&15  (m89-verified)
#pragma unroll
    for (int j = 0; j < 4; ++j) {
        const int col = n0 + wc * 64 + j * 16 + r16;
        const float bv = bias[col];
#pragma unroll
        for (int i = 0; i < 4; ++i) {
            const int rbase = m0 + wr * 64 + i * 16 + g * 4;
#pragma unroll
            for (int rr = 0; rr < 4; ++rr) {
                float vv = acc[i][j][rr] + bv;
                if (OUT_BF16)
                    ((bf16_t*)Cout)[(size_t)(rbase + rr) * DMODEL + col] = (bf16_t)vv;
                else
                    ((float*)Cout)[(size_t)(rbase + rr) * DMODEL + col] = vv;
            }
        }
    }
}

// ---------------------------------------------------------------------------
// MFMA flash attention, swapped-QK^T + in-register base-2 softmax + defer-max.
// Block = (b, h, 64-query tile), 4 waves, 16 q-rows/wave.
// S computed as mfma(K,Q): lane&15 = q-row -> row max/sum is in-register
// (16 values) + 2 shfl_xor. P packed bf16x4 -> 4 x b64 LDS writes.
// ---------------------------------------------------------------------------
__global__ __launch_bounds__(256) void flash_mfma(
    const bf16_t* __restrict__ qg, const bf16_t* __restrict__ kg,
    const bf16_t* __restrict__ vg, bf16_t* __restrict__ ctx)
{
    __shared__ bf16_t Ks[64 * 64];   // [key][dim], byte ^= (key&7)<<4
    __shared__ bf16_t Vt[64 * 72];   // [dim][key], padded pitch 72
    __shared__ bf16_t Ps[64 * 72];   // [q][key],  padded pitch 72

    const int t = threadIdx.x;
    const int w = t >> 6, lane = t & 63;
    const int r16 = lane & 15, g = lane >> 4;
    const int g4 = g * 4;
    const int q0 = blockIdx.x * 64, h = blockIdx.y, b = blockIdx.z;

    // Q fragments in registers: row = q0+16w+r16, k = kc*32 + g*8 + j
    bf16x8 qf0, qf1;
    {
        const bf16_t* qrow = qg + (size_t)(b * SEQ + q0 + 16 * w + r16) * DMODEL + h * DHEAD;
        qf0 = *(const bf16x8*)&qrow[g * 8];
        qf1 = *(const bf16x8*)&qrow[32 + g * 8];
    }

    // K staging: issue r: dest byte y = r*4096 + w*1024 + lane*16
    const int yk0 = w * 1024 + lane * 16;
    const int yk1 = yk0 + 4096;
    const int kr0 = yk0 >> 7, kr1 = yk1 >> 7;
    const int ks0 = ((yk0 >> 4) & 7) ^ (kr0 & 7);
    const int ks1 = ((yk1 >> 4) & 7) ^ (kr1 & 7);
    const bf16_t* kb0 = kg + (size_t)(b * SEQ + kr0) * DMODEL + h * DHEAD + ks0 * 8;
    const bf16_t* kb1 = kg + (size_t)(b * SEQ + kr1) * DMODEL + h * DHEAD + ks1 * 8;
    bf16_t* kd0 = Ks + w * 512;
    bf16_t* kd1 = Ks + 2048 + w * 512;

    // V staging: this thread loads key=lane, dims [w*16, w*16+16)
    const bf16_t* vb = vg + (size_t)(b * SEQ + lane) * DMODEL + h * DHEAD + w * 16;

    // K fragment offsets (elements), swizzled
    int koff[4][2];
#pragma unroll
    for (int nj = 0; nj < 4; ++nj) {
        const int key = nj * 16 + r16;
#pragma unroll
        for (int kc = 0; kc < 2; ++kc) {
            int lin = key * 128 + kc * 64 + g * 16;
            lin ^= (key & 7) << 4;
            koff[nj][kc] = lin >> 1;
        }
    }

    const f32x4 z4 = {0.f, 0.f, 0.f, 0.f};
    // softmax state per lane: q-row = r16 of this wave, base-2 domain
    float m2 = -1e30f, l2 = 0.f;
    f32x4 o_[4];                       // [dv-block]; rows = q = g*4+rr
#pragma unroll
    for (int i = 0; i < 4; ++i) o_[i] = z4;

    const float C2 = 0.1803368801f;    // (1/8) * log2(e)
    const float THR2 = 11.5416f;       // 8 * log2(e)

    for (int kv0 = 0; kv0 < SEQ; kv0 += 64) {
        // V tile -> regs early (latency hides under barrier/stage)
        const bf16_t* vv = vb + (size_t)kv0 * DMODEL;
        bf16x8 v0 = *(const bf16x8*)&vv[0];
        bf16x8 v1 = *(const bf16x8*)&vv[8];
        __syncthreads();   // prior reads of Ks/Vt/Ps complete
        gload_lds16(kb0 + (size_t)kv0 * DMODEL, kd0);
        gload_lds16(kb1 + (size_t)kv0 * DMODEL, kd1);
#pragma unroll
        for (int e = 0; e < 8; ++e) {
            Vt[(w * 16 + e) * 72 + lane]     = v0[e];
            Vt[(w * 16 + 8 + e) * 72 + lane] = v1[e];
        }
        __syncthreads();   // K staged (barrier drains vmcnt), Vt visible

        // S^T = K Q^T : s[nj][rr] = S[key = nj*16+g*4+rr][q = 16w+r16]
        f32x4 s[4];
        __builtin_amdgcn_s_setprio(1);
#pragma unroll
        for (int nj = 0; nj < 4; ++nj) {
            bf16x8 kf0 = *(const bf16x8*)&Ks[koff[nj][0]];
            bf16x8 kf1 = *(const bf16x8*)&Ks[koff[nj][1]];
            s[nj] = __builtin_amdgcn_mfma_f32_16x16x32_bf16(kf0, qf0, z4, 0, 0, 0);
            s[nj] = __builtin_amdgcn_mfma_f32_16x16x32_bf16(kf1, qf1, s[nj], 0, 0, 0);
        }
        __builtin_amdgcn_s_setprio(0);

        // row max over this lane's 16 scores (one q-row) + reduce over g
        float mm[4];
#pragma unroll
        for (int nj = 0; nj < 4; ++nj)
            mm[nj] = fmaxf(fmaxf(s[nj][0], s[nj][1]), fmaxf(s[nj][2], s[nj][3]));
        float mx2 = fmaxf(fmaxf(mm[0], mm[1]), fmaxf(mm[2], mm[3])) * C2;
        mx2 = fmaxf(mx2, __shfl_xor(mx2, 16));
        mx2 = fmaxf(mx2, __shfl_xor(mx2, 32));

        // defer-max: rescale only when the max moved by > 8 (nat-log units)
        if (!__all(mx2 - m2 <= THR2)) {
            const float mnew = fmaxf(m2, mx2);
            const float fs = exp2f(m2 - mnew);
            m2 = mnew;
            l2 *= fs;
            const float f0 = __shfl(fs, g4 + 0, 16);
            const float f1 = __shfl(fs, g4 + 1, 16);
            const float f2 = __shfl(fs, g4 + 2, 16);
            const float f3 = __shfl(fs, g4 + 3, 16);
#pragma unroll
            for (int nj = 0; nj < 4; ++nj) {
                f32x4 t4 = o_[nj];
                t4[0] *= f0; t4[1] *= f1; t4[2] *= f2; t4[3] *= f3;
                o_[nj] = t4;
            }
        }

        // P = exp2(s*C2 - m2), row-sum in-register + 2 shfl
        float p[4][4];
        float rs = 0.f;
#pragma unroll
        for (int nj = 0; nj < 4; ++nj)
#pragma unroll
            for (int rr = 0; rr < 4; ++rr) {
                p[nj][rr] = exp2f(s[nj][rr] * C2 - m2);
                rs += p[nj][rr];
            }
        rs += __shfl_xor(rs, 16);
        rs += __shfl_xor(rs, 32);
        l2 += rs;

        // pack 4 consecutive keys -> b64 write: Ps[q=16w+r16][nj*16+g4 ..]
#pragma unroll
        for (int nj = 0; nj < 4; ++nj) {
            bf16x4 pk;
            pk[0] = (bf16_t)p[nj][0]; pk[1] = (bf16_t)p[nj][1];
            pk[2] = (bf16_t)p[nj][2]; pk[3] = (bf16_t)p[nj][3];
            *(bf16x4*)&Ps[(16 * w + r16) * 72 + nj * 16 + g4] = pk;
        }
        __syncthreads();   // Ps visible

        // O += P V : A-frag from Ps, B-frag from Vt
        bf16x8 pf0 = *(const bf16x8*)&Ps[(16 * w + r16) * 72 + g * 8];
        bf16x8 pf1 = *(const bf16x8*)&Ps[(16 * w + r16) * 72 + 32 + g * 8];
        __builtin_amdgcn_s_setprio(1);
#pragma unroll
        for (int nj = 0; nj < 4; ++nj) {
            bf16x8 vf0 = *(const bf16x8*)&Vt[(nj * 16 + r16) * 72 + g * 8];
            bf16x8 vf1 = *(const bf16x8*)&Vt[(nj * 16 + r16) * 72 + 32 + g * 8];
            o_[nj] = __builtin_amdgcn_mfma_f32_16x16x32_bf16(pf0, vf0, o_[nj], 0, 0, 0);
            o_[nj] = __builtin_amdgcn_mfma_f32_16x16x32_bf16(pf1, vf1, o_[nj], 0, 0, 0);
        }
        __builtin_amdgcn_s_setprio(0);
    }

    // write context (bf16): o_ rows are q = g*4+rr; l lives at lane q=r16
#pragma unroll
    for (int rr = 0; rr < 4; ++rr) {
        const float lv = __shfl(l2, g4 + rr, 16);
        const float inv = 1.0f / lv;
        const size_t rowbase =
            (size_t)(b * SEQ + q0 + 16 * w + g4 + rr) * DMODEL + h * DHEAD;
#pragma unroll
        for (int nj = 0; nj < 4; ++nj)
            ctx[rowbase + nj * 16 + r16] = (bf16_t)(o_[nj][rr] * inv);
    }
}

// ---------------------------------------------------------------------------
// out = LayerNorm(x + res) * g + b, rows of 1024. One block per row.
// ---------------------------------------------------------------------------
__global__ __launch_bounds__(256) void ln_residual(
    const float* __restrict__ x, const float* __restrict__ res,
    const float* __restrict__ g, const float* __restrict__ bb,
    float* __restrict__ out)
{
    const int row = blockIdx.x;
    const int t = threadIdx.x;
    f4 xv = *(const f4*)&x[(size_t)row * DMODEL + t * 4];
    f4 rv = *(const f4*)&res[(size_t)row * DMODEL + t * 4];
    f4 v;
#pragma unroll
    for (int u = 0; u < 4; ++u) v[u] = xv[u] + rv[u];

    float s = 0.f, s2 = 0.f;
#pragma unroll
    for (int u = 0; u < 4; ++u) { s += v[u]; s2 += v[u] * v[u]; }
#pragma unroll
    for (int off = 1; off < 64; off <<= 1) {
        s  += __shfl_xor(s, off);
        s2 += __shfl_xor(s2, off);
    }
    __shared__ float red[2][4];
    const int wid = t >> 6, lane = t & 63;
    if (lane == 0) { red[0][wid] = s; red[1][wid] = s2; }
    __syncthreads();
    s  = red[0][0] + red[0][1] + red[0][2] + red[0][3];
    s2 = red[1][0] + red[1][1] + red[1][2] + red[1][3];

    const float mean = s * (1.0f / DMODEL);
    const float var  = s2 * (1.0f / DMODEL) - mean * mean;
    const float rstd = rsqrtf(var + LN_EPS);

    f4 gv = *(const f4*)&g[t * 4];
    f4 bv = *(const f4*)&bb[t * 4];
    f4 ov;
#pragma unroll
    for (int u = 0; u < 4; ++u) ov[u] = (v[u] - mean) * rstd * gv[u] + bv[u];
    *(f4*)&out[(size_t)row * DMODEL + t * 4] = ov;
}

// ---------------------------------------------------------------------------
extern "C" void kernel_launch(void* const* d_in, const int* in_sizes, int n_in,
                              void* d_out, int out_size, void* d_ws, size_t ws_size,
                              hipStream_t stream)
{
    const float* Q   = (const float*)d_in[0];
    const float* Wq  = (const float*)d_in[1];
    const float* bq  = (const float*)d_in[2];
    const float* Wk  = (const float*)d_in[3];
    const float* bk  = (const float*)d_in[4];
    const float* Wv  = (const float*)d_in[5];
    const float* bv  = (const float*)d_in[6];
    const float* Wo  = (const float*)d_in[7];
    const float* bo  = (const float*)d_in[8];
    const float* lng = (const float*)d_in[9];
    const float* lnb = (const float*)d_in[10];

    char* wsb = (char*)d_ws;
    // 0..16M: Qbf | 16..32M: q/ctx | 32..48M: k | 48..64M: v
    // 32..64M (after attn): attn_out fp32 | 64..72M: transposed bf16 weights
    bf16_t* Qbf  = (bf16_t*)(wsb);
    bf16_t* qb   = (bf16_t*)(wsb + (size_t)(16 << 20));
    bf16_t* kb   = (bf16_t*)(wsb + (size_t)(32 << 20));
    bf16_t* vbuf = (bf16_t*)(wsb + (size_t)(48 << 20));
    float*  ao   = (float*) (wsb + (size_t)(32 << 20));
    bf16_t* Wqt  = (bf16_t*)(wsb + (size_t)(64 << 20));
    bf16_t* Wkt  = (bf16_t*)(wsb + (size_t)(66 << 20));
    bf16_t* Wvt  = (bf16_t*)(wsb + (size_t)(68 << 20));
    bf16_t* Wot  = (bf16_t*)(wsb + (size_t)(70 << 20));

    cvt_bf16<<<2048, 256, 0, stream>>>(Q, Qbf, MTOT * DMODEL / 4);
    dim3 wg(32, 32);
    wtrans<<<wg, 256, 0, stream>>>(Wq, Wqt);
    wtrans<<<wg, 256, 0, stream>>>(Wk, Wkt);
    wtrans<<<wg, 256, 0, stream>>>(Wv, Wvt);
    wtrans<<<wg, 256, 0, stream>>>(Wo, Wot);

    dim3 gg(DMODEL / 128, MTOT / 128);            // (8, 64)
    gemm_mfma<1><<<gg, 256, 0, stream>>>(Qbf, Wqt, bq, qb);
    gemm_mfma<1><<<gg, 256, 0, stream>>>(Qbf, Wkt, bk, kb);
    gemm_mfma<1><<<gg, 256, 0, stream>>>(Qbf, Wvt, bv, vbuf);

    dim3 ga(SEQ / 64, NHEAD, BATCH);              // (32, 16, 4)
    flash_mfma<<<ga, 256, 0, stream>>>(qb, kb, vbuf, qb);  // ctx aliases q

    gemm_mfma<0><<<gg, 256, 0, stream>>>(qb, Wot, bo, ao);

    ln_residual<<<MTOT, 256, 0, stream>>>(ao, Q, lng, lnb, (float*)d_out);
}